// Round 3
// baseline (509.428 us; speedup 1.0000x reference)
//
#include <hip/hip_runtime.h>
#include <hip/hip_bf16.h>

#define PW 64
#define NV 512
#define HW 256
#define COV 16
#define BATCH 2048
#define XROW (PW * NV + COV)   // 32784
#define IMG 16384              // shorts per (pathway, k-block) weight image: 256 n x 64 k
#define AIMG 4096              // shorts per (p, mtile, kb) H1 image: 64 rows x 64 k

typedef short s16x8 __attribute__((ext_vector_type(8)));
typedef float f32x4 __attribute__((ext_vector_type(4)));

__device__ __forceinline__ unsigned short f2bf(float f) {
    union { float f; unsigned int u; } v;
    v.f = f;
    unsigned int u = v.u;
    unsigned int r = (u + 0x7fffu + ((u >> 16) & 1u)) >> 16;   // RNE
    return (unsigned short)r;
}

// packed f32x2 -> bf16x2 (v_cvt_pk_bf16_f32 on gfx950, RNE)
__device__ __forceinline__ unsigned int pack2(float a, float b) {
    __hip_bfloat162 h = __float22bfloat162_rn(float2{a, b});
    union { __hip_bfloat162 h; unsigned int u; } c;
    c.h = h;
    return c.u;
}

__device__ __forceinline__ float lrelu(float v) { return v >= 0.f ? v : 0.2f * v; }

// async global->LDS, 16 bytes per lane; LDS dest = wave-uniform base + lane*16
__device__ __forceinline__ void gl_lds16(const void* g, void* l) {
    __builtin_amdgcn_global_load_lds(
        (const __attribute__((address_space(1))) void*)g,
        (__attribute__((address_space(3))) void*)l, 16, 0, 0);
}

// ---------------------------------------------------------------------------
// Weight prep: fp32 [P][K][N] -> bf16 staging images, one 32 KB image per
// (pathway, 64-wide k-block):  shorts[n*64 + s*8 + j] = W[kb*64 + (s^(n&7))*8 + j][n]
// (N-major transpose with 16B-granule XOR swizzle pre-applied, so the GEMMs
//  can global_load_lds linearly and ds_read_b128 conflict-free.)
// ---------------------------------------------------------------------------
__global__ __launch_bounds__(256)
void transpose_all(const float* __restrict__ W1, const float* __restrict__ W2,
                   unsigned short* __restrict__ W1I, unsigned short* __restrict__ W2I) {
    __shared__ float tile[64][260];    // 64 k-rows x 256 n, pad 4 floats
    int bx = blockIdx.x;
    const float* src;
    unsigned short* dst;
    if (bx < 512) {                    // W1 slab
        int p = bx >> 3, kb = bx & 7;
        src = W1 + ((size_t)p * NV + kb * 64) * HW;
        dst = W1I + (size_t)(p * 8 + kb) * IMG;
    } else {                           // W2 slab
        bx -= 512;
        int p = bx >> 2, kb = bx & 3;
        src = W2 + ((size_t)p * HW + kb * 64) * HW;
        dst = W2I + (size_t)(p * 4 + kb) * IMG;
    }
    const int t = threadIdx.x;
    #pragma unroll
    for (int i = 0; i < 16; ++i) {     // coalesced load of 64x256 f32 slab
        int idx = t + i * 256;         // float4 index 0..4095
        int r = idx >> 6, c4 = (idx & 63) << 2;
        *(float4*)&tile[r][c4] = *(const float4*)(src + (size_t)r * HW + c4);
    }
    __syncthreads();
    #pragma unroll
    for (int pass = 0; pass < 8; ++pass) {
        int idx = pass * 256 + t;      // output granule index 0..2047
        int n = idx >> 3, s = idx & 7;
        int g = s ^ (n & 7);           // slot s stores k-granule g
        unsigned short v[8];
        #pragma unroll
        for (int j = 0; j < 8; ++j)
            v[j] = f2bf(tile[g * 8 + j][n]);
        *(s16x8*)(dst + (size_t)idx * 8) = *(s16x8*)v;   // coalesced 16B stores
    }
}

// ---------------------------------------------------------------------------
// gemm1: per (pathway, 64-row tile)  H1 = lrelu(x_p @ W1_p), bf16 out, written
// in the swizzled 64x64 image layout gemm2 consumes via global_load_lds.
// Single-barrier-per-k-step pipeline: As dbuf (reg-staged, ping-pong reg sets,
// loads issued at step START), Bs dbuf (global_load_lds).  LDS = 80 KB exactly
// -> 2 blocks/CU.
// ---------------------------------------------------------------------------
__global__ __launch_bounds__(256, 2)
void gemm1(const float* __restrict__ x, const unsigned short* __restrict__ W1I,
           unsigned short* __restrict__ H1I) {
    __shared__ __align__(16) unsigned short As[2][64 * 64];    // 2 x 8 KB
    __shared__ __align__(16) unsigned short Bs[2][256 * 64];   // 2 x 32 KB

    // XCD-aware remap: each XCD owns 8 whole pathways (weights L2-resident)
    const int lin = blockIdx.x;            // 0..2047
    const int xcd = lin & 7;
    const int idx = lin >> 3;              // 0..255
    const int p   = xcd * 8 + (idx >> 5);
    const int m   = idx & 31;
    const int bm0 = m * 64;

    const int t = threadIdx.x;
    const int lane = t & 63;
    const int wave = t >> 6;
    const int wn   = wave * 64;
    const int l15  = lane & 15;
    const int quad = lane >> 4;

    const float* Ap          = x   + (size_t)p * NV;
    const unsigned short* B1 = W1I + (size_t)p * 8 * IMG;

    // per-thread As staging addresses (4 uint2 writes, swizzled)
    int arow[4], acol[4], aoff[4];
    #pragma unroll
    for (int i = 0; i < 4; ++i) {
        int ii = t + i * 256;
        arow[i] = ii >> 4;
        acol[i] = (ii & 15) * 4;
        int slot = (acol[i] >> 3) ^ (arow[i] & 7);
        aoff[i] = arow[i] * 64 + slot * 8 + (acol[i] & 7);
    }

    float4 aA[4], aB[4];

#define XLOAD(dst, k0) { \
    _Pragma("unroll") \
    for (int i = 0; i < 4; ++i) \
        dst[i] = *(const float4*)(Ap + (size_t)(bm0 + arow[i]) * XROW + (k0) + acol[i]); }

#define APACK(src, buf) { \
    _Pragma("unroll") \
    for (int i = 0; i < 4; ++i) { \
        uint2 u; \
        u.x = pack2(src[i].x, src[i].y); \
        u.y = pack2(src[i].z, src[i].w); \
        *(uint2*)&As[buf][aoff[i]] = u; } }

#define B1STAGE(buf, kb) { \
    const unsigned short* img = B1 + (size_t)(kb) * IMG; \
    _Pragma("unroll") \
    for (int c = 0; c < 8; ++c) { \
        int off = wave * 8192 + c * 1024; \
        gl_lds16((const char*)img + off + lane * 16, (char*)Bs[buf] + off); } }

#define MFMA1(buf) { \
    _Pragma("unroll") \
    for (int kk = 0; kk < 64; kk += 32) { \
        s16x8 af[4], bfr[4]; \
        _Pragma("unroll") \
        for (int mi = 0; mi < 4; ++mi) { \
            int row = mi * 16 + l15; \
            int slot = ((kk >> 3) + quad) ^ (row & 7); \
            af[mi] = *(const s16x8*)&As[buf][row * 64 + slot * 8]; } \
        _Pragma("unroll") \
        for (int ni = 0; ni < 4; ++ni) { \
            int row = wn + ni * 16 + l15; \
            int slot = ((kk >> 3) + quad) ^ (row & 7); \
            bfr[ni] = *(const s16x8*)&Bs[buf][row * 64 + slot * 8]; } \
        _Pragma("unroll") \
        for (int mi = 0; mi < 4; ++mi) \
            _Pragma("unroll") \
            for (int ni = 0; ni < 4; ++ni) \
                acc[mi][ni] = __builtin_amdgcn_mfma_f32_16x16x32_bf16( \
                    af[mi], bfr[ni], acc[mi][ni], 0, 0, 0); } }

    // prologue: slice 0 into buf 0; slice-1 regs in flight
    XLOAD(aA, 0);
    B1STAGE(0, 0);
    APACK(aA, 0);          // waits slice-0 regs (once)
    XLOAD(aA, 64);         // slice 1 -> packed during step 0
    __syncthreads();

    f32x4 acc[4][4] = {};

    // 8 k-steps, unrolled x2 for reg ping-pong; even: load aB / pack aA
    #pragma unroll
    for (int s2 = 0; s2 < 4; ++s2) {
        const int te = 2 * s2;
        if (te + 1 < 8) B1STAGE((te + 1) & 1, te + 1);
        if (te + 2 < 8) XLOAD(aB, (te + 2) * 64);
        MFMA1(te & 1);
        if (te + 1 < 8) APACK(aA, (te + 1) & 1);
        __syncthreads();
        const int to = te + 1;
        if (to + 1 < 8) B1STAGE((to + 1) & 1, to + 1);
        if (to + 2 < 8) XLOAD(aA, (to + 2) * 64);
        MFMA1(to & 1);
        if (to + 1 < 8) APACK(aB, (to + 1) & 1);
        __syncthreads();
    }

    // epilogue: lrelu + bf16 into swizzled H1 image (wave w = k-block w)
    unsigned short* Hp = H1I + ((size_t)(p * 32 + m) * 4 + wave) * AIMG;
    #pragma unroll
    for (int mi = 0; mi < 4; ++mi)
        #pragma unroll
        for (int ni = 0; ni < 4; ++ni)
            #pragma unroll
            for (int r = 0; r < 4; ++r) {
                int row = mi * 16 + quad * 4 + r;
                int col = ni * 16 + l15;
                int slot = (col >> 3) ^ (row & 7);
                Hp[row * 64 + slot * 8 + (col & 7)] = f2bf(lrelu(acc[mi][ni][r]));
            }
#undef XLOAD
#undef APACK
#undef B1STAGE
#undef MFMA1
}

// ---------------------------------------------------------------------------
// gemm2: per (pathway, 64-row tile)  H2 = lrelu(H1 @ W2), fused W3-dot ->
// pvec[p][row].  Both operands staged purely via global_load_lds from
// pre-swizzled images; one barrier per k-step.  LDS = 80 KB -> 2 blocks/CU.
// ---------------------------------------------------------------------------
__global__ __launch_bounds__(256, 2)
void gemm2(const unsigned short* __restrict__ H1I, const unsigned short* __restrict__ W2I,
           const float* __restrict__ W3, float* __restrict__ pvec) {
    __shared__ __align__(16) unsigned short As[2][64 * 64];    // 2 x 8 KB
    __shared__ __align__(16) unsigned short Bs[2][256 * 64];   // 2 x 32 KB

    const int lin = blockIdx.x;
    const int xcd = lin & 7;
    const int idx = lin >> 3;
    const int p   = xcd * 8 + (idx >> 5);
    const int m   = idx & 31;
    const int bm0 = m * 64;

    const int t = threadIdx.x;
    const int lane = t & 63;
    const int wave = t >> 6;
    const int wn   = wave * 64;
    const int l15  = lane & 15;
    const int quad = lane >> 4;

    const unsigned short* Aimg = H1I + (size_t)(p * 32 + m) * 4 * AIMG;
    const unsigned short* B2   = W2I + (size_t)p * 4 * IMG;

#define A2STAGE(buf, kb) { \
    const unsigned short* img = Aimg + (size_t)(kb) * AIMG; \
    _Pragma("unroll") \
    for (int c = 0; c < 2; ++c) { \
        int off = wave * 2048 + c * 1024; \
        gl_lds16((const char*)img + off + lane * 16, (char*)As[buf] + off); } }

#define B2STAGE(buf, kb) { \
    const unsigned short* img = B2 + (size_t)(kb) * IMG; \
    _Pragma("unroll") \
    for (int c = 0; c < 8; ++c) { \
        int off = wave * 8192 + c * 1024; \
        gl_lds16((const char*)img + off + lane * 16, (char*)Bs[buf] + off); } }

#define MFMA2(buf) { \
    _Pragma("unroll") \
    for (int kk = 0; kk < 64; kk += 32) { \
        s16x8 af[4], bfr[4]; \
        _Pragma("unroll") \
        for (int mi = 0; mi < 4; ++mi) { \
            int row = mi * 16 + l15; \
            int slot = ((kk >> 3) + quad) ^ (row & 7); \
            af[mi] = *(const s16x8*)&As[buf][row * 64 + slot * 8]; } \
        _Pragma("unroll") \
        for (int ni = 0; ni < 4; ++ni) { \
            int row = wn + ni * 16 + l15; \
            int slot = ((kk >> 3) + quad) ^ (row & 7); \
            bfr[ni] = *(const s16x8*)&Bs[buf][row * 64 + slot * 8]; } \
        _Pragma("unroll") \
        for (int mi = 0; mi < 4; ++mi) \
            _Pragma("unroll") \
            for (int ni = 0; ni < 4; ++ni) \
                acc[mi][ni] = __builtin_amdgcn_mfma_f32_16x16x32_bf16( \
                    af[mi], bfr[ni], acc[mi][ni], 0, 0, 0); } }

    A2STAGE(0, 0);
    B2STAGE(0, 0);
    __syncthreads();

    f32x4 acc[4][4] = {};
    #pragma unroll
    for (int t4 = 0; t4 < 4; ++t4) {
        if (t4 + 1 < 4) { A2STAGE((t4 + 1) & 1, t4 + 1); B2STAGE((t4 + 1) & 1, t4 + 1); }
        MFMA2(t4 & 1);
        __syncthreads();
    }
#undef A2STAGE
#undef B2STAGE
#undef MFMA2

    // W3-dot epilogue (H2 stays f32 in registers); red overlaid on dead As
    float* red = (float*)&As[0][0];     // 4 waves x 64 rows
    float w3v[4];
    #pragma unroll
    for (int ni = 0; ni < 4; ++ni)
        w3v[ni] = W3[(size_t)p * HW + wn + ni * 16 + l15];
    float part[4][4];
    #pragma unroll
    for (int mi = 0; mi < 4; ++mi) {
        #pragma unroll
        for (int r = 0; r < 4; ++r) {
            float s = 0.f;
            #pragma unroll
            for (int ni = 0; ni < 4; ++ni)
                s += lrelu(acc[mi][ni][r]) * w3v[ni];
            part[mi][r] = s;
        }
    }
    #pragma unroll
    for (int off = 1; off < 16; off <<= 1)
        #pragma unroll
        for (int mi = 0; mi < 4; ++mi)
            #pragma unroll
            for (int r = 0; r < 4; ++r)
                part[mi][r] += __shfl_xor(part[mi][r], off);
    if (l15 == 0)
        #pragma unroll
        for (int mi = 0; mi < 4; ++mi)
            #pragma unroll
            for (int r = 0; r < 4; ++r)
                red[wave * 64 + mi * 16 + quad * 4 + r] = part[mi][r];
    __syncthreads();
    if (t < 64) {
        float s = red[0 * 64 + t] + red[1 * 64 + t] + red[2 * 64 + t] + red[3 * 64 + t];
        pvec[(size_t)p * BATCH + bm0 + t] = lrelu(s);
    }
}

// ---------------------------------------------------------------------------
// Per-pathway batch stats: mean, invstd, var.  64 blocks, one per pathway.
// ---------------------------------------------------------------------------
__global__ __launch_bounds__(256)
void stats_k(const float* __restrict__ pvec, float* __restrict__ stat) {
    const int p = blockIdx.x;
    float s = 0.f, q = 0.f;
    for (int i = threadIdx.x; i < BATCH; i += 256) {
        float v = pvec[(size_t)p * BATCH + i];
        s += v; q += v * v;
    }
    #pragma unroll
    for (int off = 32; off; off >>= 1) {
        s += __shfl_down(s, off);
        q += __shfl_down(q, off);
    }
    __shared__ float ls[4], lq[4];
    const int wave = threadIdx.x >> 6, lane = threadIdx.x & 63;
    if (lane == 0) { ls[wave] = s; lq[wave] = q; }
    __syncthreads();
    if (threadIdx.x == 0) {
        float S = ls[0] + ls[1] + ls[2] + ls[3];
        float Q = lq[0] + lq[1] + lq[2] + lq[3];
        float mean = S * (1.f / BATCH);
        float var  = Q * (1.f / BATCH) - mean * mean;
        stat[p]       = mean;
        stat[64 + p]  = rsqrtf(var + 1e-5f);
        stat[128 + p] = var;
    }
}

// ---------------------------------------------------------------------------
// Final: closed-form global norm, batchnorm-apply, /norm, covariates, linear,
// sigmoid.
// ---------------------------------------------------------------------------
__global__ __launch_bounds__(256)
void final_k(const float* __restrict__ pvec, const float* __restrict__ stat,
             const float* __restrict__ gamma, const float* __restrict__ beta,
             const float* __restrict__ x, const float* __restrict__ fc_w,
             const float* __restrict__ fc_b, float* __restrict__ out) {
    const int b = blockIdx.x * 256 + threadIdx.x;
    float nsq = 0.f;
    #pragma unroll
    for (int p = 0; p < PW; ++p) {
        float g = gamma[p], bt = beta[p], var = stat[128 + p], inv = stat[64 + p];
        nsq += (float)BATCH * (g * g * var * inv * inv + bt * bt);
    }
    const float rn = rsqrtf(nsq);
    float acc = fc_b[0];
    #pragma unroll
    for (int p = 0; p < PW; ++p) {
        float pn = (pvec[(size_t)p * BATCH + b] - stat[p]) * stat[64 + p] * gamma[p] + beta[p];
        acc += pn * rn * fc_w[p];
    }
    #pragma unroll
    for (int c = 0; c < COV; ++c)
        acc += x[(size_t)b * XROW + PW * NV + c] * fc_w[PW + c];
    out[b] = 1.f / (1.f + __expf(-acc));
}

// ---------------------------------------------------------------------------
extern "C" void kernel_launch(void* const* d_in, const int* in_sizes, int n_in,
                              void* d_out, int out_size, void* d_ws, size_t ws_size,
                              hipStream_t stream) {
    const float* x     = (const float*)d_in[0];
    const float* W1    = (const float*)d_in[1];
    const float* W2    = (const float*)d_in[2];
    const float* W3    = (const float*)d_in[3];
    const float* gamma = (const float*)d_in[4];
    const float* beta  = (const float*)d_in[5];
    const float* fc_w  = (const float*)d_in[6];
    const float* fc_b  = (const float*)d_in[7];
    float* out = (float*)d_out;

    char* ws = (char*)d_ws;
    size_t off = 0;
    unsigned short* W1I = (unsigned short*)(ws + off); off += (size_t)PW * NV * HW * 2;   // 16.78 MB
    unsigned short* W2I = (unsigned short*)(ws + off); off += (size_t)PW * HW * HW * 2;   //  8.39 MB
    unsigned short* H1I = (unsigned short*)(ws + off); off += (size_t)PW * BATCH * HW * 2;//  67.1 MB
    float* pvec = (float*)(ws + off); off += (size_t)PW * BATCH * 4;                       //  0.5 MB
    float* stat = (float*)(ws + off); off += 256 * 4;

    // 1) weight transpose + bf16 convert into swizzled staging images
    transpose_all<<<dim3(512 + 256), 256, 0, stream>>>(W1, W2, W1I, W2I);

    // 2) H1 = lrelu(x @ W1)  (bf16, swizzled images)
    gemm1<<<dim3(2048), 256, 0, stream>>>(x, W1I, H1I);

    // 3) pvec = lrelu((lrelu(H1 @ W2)) . W3)
    gemm2<<<dim3(2048), 256, 0, stream>>>(H1I, W2I, W3, pvec);

    // 4) per-pathway stats (64 blocks)
    stats_k<<<PW, 256, 0, stream>>>(pvec, stat);

    // 5) final head (norm computed closed-form in-kernel)
    final_k<<<BATCH / 256, 256, 0, stream>>>(pvec, stat, gamma, beta, x, fc_w, fc_b, out);
}

// Round 4
// 488.055 us; speedup vs baseline: 1.0438x; 1.0438x over previous
//
#include <hip/hip_runtime.h>
#include <hip/hip_bf16.h>

#define PW 64
#define NV 512
#define HW 256
#define COV 16
#define BATCH 2048
#define XROW (PW * NV + COV)   // 32784
#define IMG 16384              // W1 image: 256 n x 64 k shorts (32 KB), slot = g ^ (n&7)
#define IMG2 8192              // W2 image: 256 n x 32 k shorts (16 KB), slot = g ^ ((n>>1)&3)

typedef short s16x8 __attribute__((ext_vector_type(8)));
typedef float f32x4 __attribute__((ext_vector_type(4)));

__device__ __forceinline__ unsigned short f2bf(float f) {
    union { float f; unsigned int u; } v;
    v.f = f;
    unsigned int u = v.u;
    unsigned int r = (u + 0x7fffu + ((u >> 16) & 1u)) >> 16;   // RNE
    return (unsigned short)r;
}

__device__ __forceinline__ unsigned int pack2(float a, float b) {
    __hip_bfloat162 h = __float22bfloat162_rn(float2{a, b});
    union { __hip_bfloat162 h; unsigned int u; } c;
    c.h = h;
    return c.u;
}

__device__ __forceinline__ float lrelu(float v) { return v >= 0.f ? v : 0.2f * v; }

__device__ __forceinline__ void gl_lds16(const void* g, void* l) {
    __builtin_amdgcn_global_load_lds(
        (const __attribute__((address_space(1))) void*)g,
        (__attribute__((address_space(3))) void*)l, 16, 0, 0);
}

// ---------------------------------------------------------------------------
// Weight prep.
// W1 -> 8 images/pathway of 32 KB (64-k blocks): shorts[n*64+s*8+j] =
//        W1[kb*64 + (s^(n&7))*8 + j][n]
// W2 -> 8 images/pathway of 16 KB (32-k blocks): shorts[n*32+s*8+j] =
//        W2[kb*32 + (s^((n>>1)&3))*8 + j][n]
// (transpose + bf16 + XOR swizzle pre-applied; GEMM stages linearly via
//  global_load_lds and ds_read_b128s are conflict-free.)
// ---------------------------------------------------------------------------
__global__ __launch_bounds__(256)
void transpose_all(const float* __restrict__ W1, const float* __restrict__ W2,
                   unsigned short* __restrict__ W1I, unsigned short* __restrict__ W2I) {
    __shared__ float tile[64][260];    // 64 k-rows x 256 n, pad 4 floats
    int bx = blockIdx.x;
    const int t = threadIdx.x;
    const bool isW1 = bx < 512;
    const float* src;
    if (isW1) {                        // W1 slab: 64 k x 256 n
        int p = bx >> 3, kb = bx & 7;
        src = W1 + ((size_t)p * NV + kb * 64) * HW;
    } else {
        int b2 = bx - 512;
        int p = b2 >> 2, kb64 = b2 & 3;
        src = W2 + ((size_t)p * HW + kb64 * 64) * HW;
    }
    #pragma unroll
    for (int i = 0; i < 16; ++i) {     // coalesced load of 64x256 f32 slab
        int idx = t + i * 256;         // float4 index 0..4095
        int r = idx >> 6, c4 = (idx & 63) << 2;
        *(float4*)&tile[r][c4] = *(const float4*)(src + (size_t)r * HW + c4);
    }
    __syncthreads();
    if (isW1) {
        int p = bx >> 3, kb = bx & 7;
        unsigned short* dst = W1I + (size_t)(p * 8 + kb) * IMG;
        #pragma unroll
        for (int pass = 0; pass < 8; ++pass) {
            int idx = pass * 256 + t;      // granule 0..2047
            int n = idx >> 3, s = idx & 7;
            int g = s ^ (n & 7);
            unsigned short v[8];
            #pragma unroll
            for (int j = 0; j < 8; ++j)
                v[j] = f2bf(tile[g * 8 + j][n]);
            *(s16x8*)(dst + (size_t)idx * 8) = *(s16x8*)v;
        }
    } else {
        int b2 = bx - 512;
        int p = b2 >> 2, kb64 = b2 & 3;
        unsigned short* dst = W2I + (size_t)(p * 8 + kb64 * 2) * IMG2;  // two 16 KB images
        #pragma unroll
        for (int pass = 0; pass < 8; ++pass) {
            int idx = pass * 256 + t;      // 0..2047
            int h = idx >> 10;             // which 32-k half
            int rem = idx & 1023;          // granule within image
            int n = rem >> 2, s = rem & 3;
            int g = s ^ ((n >> 1) & 3);
            int krow = h * 32 + g * 8;     // 0..63 within slab
            unsigned short v[8];
            #pragma unroll
            for (int j = 0; j < 8; ++j)
                v[j] = f2bf(tile[krow + j][n]);
            *(s16x8*)(dst + (size_t)h * IMG2 + n * 32 + s * 8) = *(s16x8*)v;
        }
    }
}

// ---------------------------------------------------------------------------
// FULLY-FUSED pathway kernel, double-buffered via LDS arena overlay (80 KB,
// 2 blocks/CU):
//   stage A (8 k-steps, BK=64): BsA dbuf 2x32K [0:64K], AsA dbuf 2x8K [64:80K]
//   stage B (8 k-steps, BK=32): H1t 32K [0:32K], W2 dbuf 2x16K [32:64K],
//                               red overlays As region.
// One barrier per k-step; stage(t+1) issued right after the barrier so
// MFMA(t) covers its latency (T3-lite/T14); s_setprio around MFMA (T5).
// ---------------------------------------------------------------------------
__global__ __launch_bounds__(256, 2)
void pathway_fused(const float* __restrict__ x, const unsigned short* __restrict__ W1I,
                   const unsigned short* __restrict__ W2I, const float* __restrict__ W3,
                   float* __restrict__ pvec) {
    __shared__ __align__(16) unsigned short lds[40960];   // 80 KB arena

    // XCD-aware remap: each XCD owns 8 whole pathways (weights L2-resident)
    const int lin = blockIdx.x;            // 0..2047
    const int xcd = lin & 7;
    const int idx = lin >> 3;              // 0..255
    const int p   = xcd * 8 + (idx >> 5);
    const int m   = idx & 31;
    const int bm0 = m * 64;

    const int t = threadIdx.x;
    const int lane = t & 63;
    const int wave = t >> 6;
    const int wn   = wave * 64;
    const int l15  = lane & 15;
    const int quad = lane >> 4;

    const float* Ap          = x   + (size_t)p * NV;
    const unsigned short* B1 = W1I + (size_t)p * 8 * IMG;
    const unsigned short* B2 = W2I + (size_t)p * 8 * IMG2;

    // per-thread As staging addresses (4 uint2 writes, swizzled)
    int arow[4], acol[4], aoff[4];
    #pragma unroll
    for (int i = 0; i < 4; ++i) {
        int ii = t + i * 256;
        arow[i] = ii >> 4;
        acol[i] = (ii & 15) * 4;
        int slot = (acol[i] >> 3) ^ (arow[i] & 7);
        aoff[i] = arow[i] * 64 + slot * 8 + (acol[i] & 7);
    }

    float4 S0[4], S1[4];
    f32x4 acc[4][4] = {};

#define XLOAD(dst, k0) { \
    _Pragma("unroll") \
    for (int i = 0; i < 4; ++i) \
        dst[i] = *(const float4*)(Ap + (size_t)(bm0 + arow[i]) * XROW + (k0) + acol[i]); }

#define APACK(src, buf) { \
    unsigned short* Asb = lds + 32768 + (buf) * 4096; \
    _Pragma("unroll") \
    for (int i = 0; i < 4; ++i) { \
        uint2 u; \
        u.x = pack2(src[i].x, src[i].y); \
        u.y = pack2(src[i].z, src[i].w); \
        *(uint2*)&Asb[aoff[i]] = u; } }

#define B1STAGE(buf, kb) { \
    const unsigned short* img = B1 + (size_t)(kb) * IMG; \
    _Pragma("unroll") \
    for (int c = 0; c < 8; ++c) { \
        int off = wave * 8192 + c * 1024; \
        gl_lds16((const char*)img + off + lane * 16, (char*)lds + (buf) * 32768 + off); } }

#define MFMA_A(buf) { \
    const unsigned short* Asb = lds + 32768 + (buf) * 4096; \
    const unsigned short* Bsb = lds + (buf) * 16384; \
    __builtin_amdgcn_s_setprio(1); \
    _Pragma("unroll") \
    for (int kk = 0; kk < 64; kk += 32) { \
        s16x8 af[4], bfr[4]; \
        _Pragma("unroll") \
        for (int mi = 0; mi < 4; ++mi) { \
            int row = mi * 16 + l15; \
            int slot = ((kk >> 3) + quad) ^ (row & 7); \
            af[mi] = *(const s16x8*)&Asb[row * 64 + slot * 8]; } \
        _Pragma("unroll") \
        for (int ni = 0; ni < 4; ++ni) { \
            int row = wn + ni * 16 + l15; \
            int slot = ((kk >> 3) + quad) ^ (row & 7); \
            bfr[ni] = *(const s16x8*)&Bsb[row * 64 + slot * 8]; } \
        _Pragma("unroll") \
        for (int mi = 0; mi < 4; ++mi) \
            _Pragma("unroll") \
            for (int ni = 0; ni < 4; ++ni) \
                acc[mi][ni] = __builtin_amdgcn_mfma_f32_16x16x32_bf16( \
                    af[mi], bfr[ni], acc[mi][ni], 0, 0, 0); } \
    __builtin_amdgcn_s_setprio(0); }

#define W2STAGE(buf, kb) { \
    const unsigned short* img = B2 + (size_t)(kb) * IMG2; \
    _Pragma("unroll") \
    for (int c = 0; c < 4; ++c) { \
        int off = wave * 4096 + c * 1024; \
        gl_lds16((const char*)img + off + lane * 16, (char*)lds + 32768 + (buf) * 16384 + off); } }

#define MFMA_B(buf, kb) { \
    const unsigned short* W2b = lds + 16384 + (buf) * 8192; \
    __builtin_amdgcn_s_setprio(1); \
    { \
        s16x8 af[4], bfr[4]; \
        _Pragma("unroll") \
        for (int mi = 0; mi < 4; ++mi) { \
            int row = mi * 16 + l15; \
            int slot = ((kb) * 4 + quad) ^ (row & 7); \
            af[mi] = *(const s16x8*)&lds[row * 256 + slot * 8]; } \
        _Pragma("unroll") \
        for (int ni = 0; ni < 4; ++ni) { \
            int row = wn + ni * 16 + l15; \
            int slot = quad ^ ((row >> 1) & 3); \
            bfr[ni] = *(const s16x8*)&W2b[row * 32 + slot * 8]; } \
        _Pragma("unroll") \
        for (int mi = 0; mi < 4; ++mi) \
            _Pragma("unroll") \
            for (int ni = 0; ni < 4; ++ni) \
                acc[mi][ni] = __builtin_amdgcn_mfma_f32_16x16x32_bf16( \
                    af[mi], bfr[ni], acc[mi][ni], 0, 0, 0); \
    } \
    __builtin_amdgcn_s_setprio(0); }

    // ---------------- stage A: H1 = lrelu(x @ W1) ----------------
    // prologue: slice 0 staged; slice-1 x-regs in flight
    XLOAD(S0, 0);
    B1STAGE(0, 0);
    APACK(S0, 0);
    XLOAD(S0, 64);
    __syncthreads();

    #pragma unroll
    for (int s2 = 0; s2 < 4; ++s2) {
        const int te = 2 * s2;
        if (te + 1 < 8) B1STAGE(1, te + 1);
        if (te + 1 < 8) APACK(S0, 1);
        if (te + 2 < 8) XLOAD(S1, (te + 2) * 64);
        MFMA_A(0);
        __syncthreads();
        const int to = te + 1;
        if (to + 1 < 8) B1STAGE(0, to + 1);
        if (to + 1 < 8) APACK(S1, 0);
        if (to + 2 < 8) XLOAD(S0, (to + 2) * 64);
        MFMA_A(1);
        __syncthreads();
    }

    // ---------------- transition: acc -> H1t (swizzled), overlaying BsA buf0
    #pragma unroll
    for (int mi = 0; mi < 4; ++mi)
        #pragma unroll
        for (int ni = 0; ni < 4; ++ni)
            #pragma unroll
            for (int r = 0; r < 4; ++r) {
                int row = mi * 16 + quad * 4 + r;
                int col = wn + ni * 16 + l15;
                int slot = (col >> 3) ^ (row & 7);
                lds[row * 256 + slot * 8 + (col & 7)] = f2bf(lrelu(acc[mi][ni][r]));
            }
    W2STAGE(0, 0);           // into [32:48K], overlays BsA buf1 (done being read)
    __syncthreads();         // H1t visible + W2 kb0 arrived

    // ---------------- stage B: H2 = lrelu(H1 @ W2), fused W3-dot ----------
    #pragma unroll
    for (int mi = 0; mi < 4; ++mi)
        #pragma unroll
        for (int ni = 0; ni < 4; ++ni)
            acc[mi][ni] = (f32x4){0.f, 0.f, 0.f, 0.f};

    #pragma unroll
    for (int s2 = 0; s2 < 4; ++s2) {
        const int te = 2 * s2;
        if (te + 1 < 8) W2STAGE(1, te + 1);
        MFMA_B(0, te);
        __syncthreads();
        const int to = te + 1;
        if (to + 1 < 8) W2STAGE(0, to + 1);
        MFMA_B(1, to);
        __syncthreads();
    }

    // dot with W3 over this wave's 64 cols (H2 stays f32 in registers)
    float* red = (float*)(lds + 32768);   // overlays dead As region (1 KB)
    float w3v[4];
    #pragma unroll
    for (int ni = 0; ni < 4; ++ni)
        w3v[ni] = W3[(size_t)p * HW + wn + ni * 16 + l15];
    float part[4][4];
    #pragma unroll
    for (int mi = 0; mi < 4; ++mi) {
        #pragma unroll
        for (int r = 0; r < 4; ++r) {
            float s = 0.f;
            #pragma unroll
            for (int ni = 0; ni < 4; ++ni)
                s += lrelu(acc[mi][ni][r]) * w3v[ni];
            part[mi][r] = s;
        }
    }
    #pragma unroll
    for (int off = 1; off < 16; off <<= 1)
        #pragma unroll
        for (int mi = 0; mi < 4; ++mi)
            #pragma unroll
            for (int r = 0; r < 4; ++r)
                part[mi][r] += __shfl_xor(part[mi][r], off);
    if (l15 == 0)
        #pragma unroll
        for (int mi = 0; mi < 4; ++mi)
            #pragma unroll
            for (int r = 0; r < 4; ++r)
                red[wave * 64 + mi * 16 + quad * 4 + r] = part[mi][r];
    __syncthreads();
    if (t < 64) {
        float s = red[0 * 64 + t] + red[1 * 64 + t] + red[2 * 64 + t] + red[3 * 64 + t];
        pvec[(size_t)p * BATCH + bm0 + t] = lrelu(s);
    }
#undef XLOAD
#undef APACK
#undef B1STAGE
#undef MFMA_A
#undef W2STAGE
#undef MFMA_B
}

// ---------------------------------------------------------------------------
// Per-pathway batch stats: mean, invstd, var.  64 blocks, one per pathway.
// ---------------------------------------------------------------------------
__global__ __launch_bounds__(256)
void stats_k(const float* __restrict__ pvec, float* __restrict__ stat) {
    const int p = blockIdx.x;
    float s = 0.f, q = 0.f;
    for (int i = threadIdx.x; i < BATCH; i += 256) {
        float v = pvec[(size_t)p * BATCH + i];
        s += v; q += v * v;
    }
    #pragma unroll
    for (int off = 32; off; off >>= 1) {
        s += __shfl_down(s, off);
        q += __shfl_down(q, off);
    }
    __shared__ float ls[4], lq[4];
    const int wave = threadIdx.x >> 6, lane = threadIdx.x & 63;
    if (lane == 0) { ls[wave] = s; lq[wave] = q; }
    __syncthreads();
    if (threadIdx.x == 0) {
        float S = ls[0] + ls[1] + ls[2] + ls[3];
        float Q = lq[0] + lq[1] + lq[2] + lq[3];
        float mean = S * (1.f / BATCH);
        float var  = Q * (1.f / BATCH) - mean * mean;
        stat[p]       = mean;
        stat[64 + p]  = rsqrtf(var + 1e-5f);
        stat[128 + p] = var;
    }
}

// ---------------------------------------------------------------------------
// Final: closed-form global norm, batchnorm-apply, /norm, covariates, linear,
// sigmoid.
// ---------------------------------------------------------------------------
__global__ __launch_bounds__(256)
void final_k(const float* __restrict__ pvec, const float* __restrict__ stat,
             const float* __restrict__ gamma, const float* __restrict__ beta,
             const float* __restrict__ x, const float* __restrict__ fc_w,
             const float* __restrict__ fc_b, float* __restrict__ out) {
    const int b = blockIdx.x * 256 + threadIdx.x;
    float nsq = 0.f;
    #pragma unroll
    for (int p = 0; p < PW; ++p) {
        float g = gamma[p], bt = beta[p], var = stat[128 + p], inv = stat[64 + p];
        nsq += (float)BATCH * (g * g * var * inv * inv + bt * bt);
    }
    const float rn = rsqrtf(nsq);
    float acc = fc_b[0];
    #pragma unroll
    for (int p = 0; p < PW; ++p) {
        float pn = (pvec[(size_t)p * BATCH + b] - stat[p]) * stat[64 + p] * gamma[p] + beta[p];
        acc += pn * rn * fc_w[p];
    }
    #pragma unroll
    for (int c = 0; c < COV; ++c)
        acc += x[(size_t)b * XROW + PW * NV + c] * fc_w[PW + c];
    out[b] = 1.f / (1.f + __expf(-acc));
}

// ---------------------------------------------------------------------------
extern "C" void kernel_launch(void* const* d_in, const int* in_sizes, int n_in,
                              void* d_out, int out_size, void* d_ws, size_t ws_size,
                              hipStream_t stream) {
    const float* x     = (const float*)d_in[0];
    const float* W1    = (const float*)d_in[1];
    const float* W2    = (const float*)d_in[2];
    const float* W3    = (const float*)d_in[3];
    const float* gamma = (const float*)d_in[4];
    const float* beta  = (const float*)d_in[5];
    const float* fc_w  = (const float*)d_in[6];
    const float* fc_b  = (const float*)d_in[7];
    float* out = (float*)d_out;

    char* ws = (char*)d_ws;
    size_t off = 0;
    unsigned short* W1I = (unsigned short*)(ws + off); off += (size_t)PW * NV * HW * 2;  // 16.78 MB
    unsigned short* W2I = (unsigned short*)(ws + off); off += (size_t)PW * HW * HW * 2;  //  8.39 MB
    float* pvec = (float*)(ws + off); off += (size_t)PW * BATCH * 4;                      //  0.5 MB
    float* stat = (float*)(ws + off); off += 256 * 4;

    // 1) weight transpose + bf16 convert into swizzled staging images
    transpose_all<<<dim3(512 + 256), 256, 0, stream>>>(W1, W2, W1I, W2I);

    // 2) fully-fused pathway MLP: x -> pvec (H1 in LDS via arena overlay)
    pathway_fused<<<dim3(2048), 256, 0, stream>>>(x, W1I, W2I, W3, pvec);

    // 3) per-pathway stats (64 blocks)
    stats_k<<<PW, 256, 0, stream>>>(pvec, stat);

    // 4) final head (norm computed closed-form in-kernel)
    final_k<<<BATCH / 256, 256, 0, stream>>>(pvec, stat, gamma, beta, x, fc_w, fc_b, out);
}

// Round 5
// 481.078 us; speedup vs baseline: 1.0589x; 1.0145x over previous
//
#include <hip/hip_runtime.h>
#include <hip/hip_bf16.h>

#define PW 64
#define NV 512
#define HW 256
#define COV 16
#define BATCH 2048
#define XROW (PW * NV + COV)   // 32784
#define IMG 16384              // W1 image: 256 n x 64 k shorts (32 KB), slot = g ^ (n&7)
#define IMG2 8192              // W2 image: 256 n x 32 k shorts (16 KB), slot = g ^ ((n>>1)&3)

typedef short s16x8 __attribute__((ext_vector_type(8)));
typedef float f32x4 __attribute__((ext_vector_type(4)));

__device__ __forceinline__ unsigned short f2bf(float f) {
    union { float f; unsigned int u; } v;
    v.f = f;
    unsigned int u = v.u;
    unsigned int r = (u + 0x7fffu + ((u >> 16) & 1u)) >> 16;   // RNE
    return (unsigned short)r;
}

__device__ __forceinline__ unsigned int pack2(float a, float b) {
    __hip_bfloat162 h = __float22bfloat162_rn(float2{a, b});
    union { __hip_bfloat162 h; unsigned int u; } c;
    c.h = h;
    return c.u;
}

__device__ __forceinline__ float lrelu(float v) { return v >= 0.f ? v : 0.2f * v; }

__device__ __forceinline__ void gl_lds16(const void* g, void* l) {
    __builtin_amdgcn_global_load_lds(
        (const __attribute__((address_space(1))) void*)g,
        (__attribute__((address_space(3))) void*)l, 16, 0, 0);
}

// counted waitcnt + raw barrier (T4): NEVER vmcnt(0) in the steady loop
#define WAITV(n) asm volatile("s_waitcnt vmcnt(" #n ") lgkmcnt(0)" ::: "memory")
#define BAR()    __builtin_amdgcn_s_barrier()
#define SCHED0() __builtin_amdgcn_sched_barrier(0)

// ---------------------------------------------------------------------------
// Weight prep (unchanged from passing R4 version).
// W1 -> 8 images/pathway of 32 KB (64-k blocks): shorts[n*64+s*8+j] =
//        W1[kb*64 + (s^(n&7))*8 + j][n]
// W2 -> 8 images/pathway of 16 KB (32-k blocks): shorts[n*32+s*8+j] =
//        W2[kb*32 + (s^((n>>1)&3))*8 + j][n]
// ---------------------------------------------------------------------------
__global__ __launch_bounds__(256)
void transpose_all(const float* __restrict__ W1, const float* __restrict__ W2,
                   unsigned short* __restrict__ W1I, unsigned short* __restrict__ W2I) {
    __shared__ float tile[64][260];
    int bx = blockIdx.x;
    const int t = threadIdx.x;
    const bool isW1 = bx < 512;
    const float* src;
    if (isW1) {
        int p = bx >> 3, kb = bx & 7;
        src = W1 + ((size_t)p * NV + kb * 64) * HW;
    } else {
        int b2 = bx - 512;
        int p = b2 >> 2, kb64 = b2 & 3;
        src = W2 + ((size_t)p * HW + kb64 * 64) * HW;
    }
    #pragma unroll
    for (int i = 0; i < 16; ++i) {
        int idx = t + i * 256;
        int r = idx >> 6, c4 = (idx & 63) << 2;
        *(float4*)&tile[r][c4] = *(const float4*)(src + (size_t)r * HW + c4);
    }
    __syncthreads();
    if (isW1) {
        int p = bx >> 3, kb = bx & 7;
        unsigned short* dst = W1I + (size_t)(p * 8 + kb) * IMG;
        #pragma unroll
        for (int pass = 0; pass < 8; ++pass) {
            int idx = pass * 256 + t;
            int n = idx >> 3, s = idx & 7;
            int g = s ^ (n & 7);
            unsigned short v[8];
            #pragma unroll
            for (int j = 0; j < 8; ++j)
                v[j] = f2bf(tile[g * 8 + j][n]);
            *(s16x8*)(dst + (size_t)idx * 8) = *(s16x8*)v;
        }
    } else {
        int b2 = bx - 512;
        int p = b2 >> 2, kb64 = b2 & 3;
        unsigned short* dst = W2I + (size_t)(p * 8 + kb64 * 2) * IMG2;
        #pragma unroll
        for (int pass = 0; pass < 8; ++pass) {
            int idx = pass * 256 + t;
            int h = idx >> 10;
            int rem = idx & 1023;
            int n = rem >> 2, s = rem & 3;
            int g = s ^ ((n >> 1) & 3);
            int krow = h * 32 + g * 8;
            unsigned short v[8];
            #pragma unroll
            for (int j = 0; j < 8; ++j)
                v[j] = f2bf(tile[krow + j][n]);
            *(s16x8*)(dst + (size_t)h * IMG2 + n * 32 + s * 8) = *(s16x8*)v;
        }
    }
}

// ---------------------------------------------------------------------------
// FULLY-FUSED pathway kernel — R4 structure + T4 counted-vmcnt barriers.
// Arena (80 KB, 2 blocks/CU):
//   stage A: Bs dbuf 2x32K [0:64K], As dbuf 2x8K [64:80K]
//   stage B: H1t 32K [0:32K], W2 3-ring 3x16K [32:80K], red overlays [32K..]
// Steady state per A-step: weight gl_lds(t+1) covered by 1 full step;
// x-loads(t+2) stay in flight ACROSS the barrier (2 steps coverage).
// vmcnt counts (derived, per-thread, in issue order):
//   A-step t<6: issue glds(8)+xload(4); pre-barrier need glds done -> vmcnt(4)
//   A-step 6:   issue glds(8) only -> vmcnt(0);  A-step 7: nothing -> vmcnt(0)
//   B-step t<6: issue glds(4); outstanding [kb(t+1) 4, kb(t+2) 4] -> vmcnt(4)
//   B-step 6,7: vmcnt(0)
// ---------------------------------------------------------------------------
__global__ __launch_bounds__(256, 2)
void pathway_fused(const float* __restrict__ x, const unsigned short* __restrict__ W1I,
                   const unsigned short* __restrict__ W2I, const float* __restrict__ W3,
                   float* __restrict__ pvec) {
    __shared__ __align__(16) unsigned short lds[40960];   // 80 KB arena

    const int lin = blockIdx.x;            // 0..2047
    const int xcd = lin & 7;
    const int idx = lin >> 3;              // 0..255
    const int p   = xcd * 8 + (idx >> 5);  // each XCD owns 8 whole pathways
    const int m   = idx & 31;
    const int bm0 = m * 64;

    const int t = threadIdx.x;
    const int lane = t & 63;
    const int wave = t >> 6;
    const int wn   = wave * 64;
    const int l15  = lane & 15;
    const int quad = lane >> 4;

    const float* Ap          = x   + (size_t)p * NV;
    const unsigned short* B1 = W1I + (size_t)p * 8 * IMG;
    const unsigned short* B2 = W2I + (size_t)p * 8 * IMG2;

    int arow[4], aoff[4];
    #pragma unroll
    for (int i = 0; i < 4; ++i) {
        int ii = t + i * 256;
        arow[i] = ii >> 4;
        int acol = (ii & 15) * 4;
        int slot = (acol >> 3) ^ (arow[i] & 7);
        aoff[i] = arow[i] * 64 + slot * 8 + (acol & 7);
    }
    int acolc[4];
    #pragma unroll
    for (int i = 0; i < 4; ++i) acolc[i] = ((t + i * 256) & 15) * 4;

    float4 S0[4], S1[4];
    f32x4 acc[4][4] = {};

#define XLOAD(dst, k0) { \
    _Pragma("unroll") \
    for (int i = 0; i < 4; ++i) \
        dst[i] = *(const float4*)(Ap + (size_t)(bm0 + arow[i]) * XROW + (k0) + acolc[i]); }

#define APACK(src, buf) { \
    unsigned short* Asb = lds + 32768 + (buf) * 4096; \
    _Pragma("unroll") \
    for (int i = 0; i < 4; ++i) { \
        uint2 u; \
        u.x = pack2(src[i].x, src[i].y); \
        u.y = pack2(src[i].z, src[i].w); \
        *(uint2*)&Asb[aoff[i]] = u; } }

#define B1STAGE(buf, kb) { \
    const unsigned short* img = B1 + (size_t)(kb) * IMG; \
    _Pragma("unroll") \
    for (int c = 0; c < 8; ++c) { \
        int off = wave * 8192 + c * 1024; \
        gl_lds16((const char*)img + off + lane * 16, (char*)lds + (buf) * 32768 + off); } }

#define MFMA_A(buf) { \
    const unsigned short* Asb = lds + 32768 + (buf) * 4096; \
    const unsigned short* Bsb = lds + (buf) * 16384; \
    __builtin_amdgcn_s_setprio(1); \
    _Pragma("unroll") \
    for (int kk = 0; kk < 64; kk += 32) { \
        s16x8 af[4], bfr[4]; \
        _Pragma("unroll") \
        for (int mi = 0; mi < 4; ++mi) { \
            int row = mi * 16 + l15; \
            int slot = ((kk >> 3) + quad) ^ (row & 7); \
            af[mi] = *(const s16x8*)&Asb[row * 64 + slot * 8]; } \
        _Pragma("unroll") \
        for (int ni = 0; ni < 4; ++ni) { \
            int row = wn + ni * 16 + l15; \
            int slot = ((kk >> 3) + quad) ^ (row & 7); \
            bfr[ni] = *(const s16x8*)&Bsb[row * 64 + slot * 8]; } \
        _Pragma("unroll") \
        for (int mi = 0; mi < 4; ++mi) \
            _Pragma("unroll") \
            for (int ni = 0; ni < 4; ++ni) \
                acc[mi][ni] = __builtin_amdgcn_mfma_f32_16x16x32_bf16( \
                    af[mi], bfr[ni], acc[mi][ni], 0, 0, 0); } \
    __builtin_amdgcn_s_setprio(0); }

#define W2STAGE(buf, kb) { \
    const unsigned short* img = B2 + (size_t)(kb) * IMG2; \
    _Pragma("unroll") \
    for (int c = 0; c < 4; ++c) { \
        int off = wave * 4096 + c * 1024; \
        gl_lds16((const char*)img + off + lane * 16, (char*)lds + 16384 + (buf) * 8192 + off); } }

#define MFMA_B(buf, kb) { \
    const unsigned short* W2b = lds + 16384 + (buf) * 8192; \
    __builtin_amdgcn_s_setprio(1); \
    { \
        s16x8 af[4], bfr[4]; \
        _Pragma("unroll") \
        for (int mi = 0; mi < 4; ++mi) { \
            int row = mi * 16 + l15; \
            int slot = ((kb) * 4 + quad) ^ (row & 7); \
            af[mi] = *(const s16x8*)&lds[row * 256 + slot * 8]; } \
        _Pragma("unroll") \
        for (int ni = 0; ni < 4; ++ni) { \
            int row = wn + ni * 16 + l15; \
            int slot = quad ^ ((row >> 1) & 3); \
            bfr[ni] = *(const s16x8*)&W2b[row * 32 + slot * 8]; } \
        _Pragma("unroll") \
        for (int mi = 0; mi < 4; ++mi) \
            _Pragma("unroll") \
            for (int ni = 0; ni < 4; ++ni) \
                acc[mi][ni] = __builtin_amdgcn_mfma_f32_16x16x32_bf16( \
                    af[mi], bfr[ni], acc[mi][ni], 0, 0, 0); \
    } \
    __builtin_amdgcn_s_setprio(0); }

// stage-A step: issue glds(t+1), xload(t+2), pack(t+1), mfma(t); counted wait
#define STEP_A(tt, sLoad, sPack, WN) { \
    if ((tt) + 1 < 8) B1STAGE(1 - ((tt) & 1), (tt) + 1); \
    SCHED0(); \
    if ((tt) + 2 < 8) XLOAD(sLoad, ((tt) + 2) * 64); \
    if ((tt) + 1 < 8) APACK(sPack, 1 - ((tt) & 1)); \
    MFMA_A((tt) & 1); \
    WAITV(WN); \
    BAR(); \
    SCHED0(); }

#define STEP_B(tt, WN) { \
    if ((tt) + 2 < 8) W2STAGE(((tt) + 2) % 3, (tt) + 2); \
    SCHED0(); \
    MFMA_B((tt) % 3, (tt)); \
    WAITV(WN); \
    BAR(); \
    SCHED0(); }

    // ---------------- stage A prologue: pinned issue order x0, glds0, x1 ----
    XLOAD(S0, 0);
    SCHED0();
    B1STAGE(0, 0);
    SCHED0();
    XLOAD(S1, 64);
    APACK(S0, 0);          // compiler waits x0 (vmcnt(12)); glds+x1 in flight
    WAITV(4);              // glds(kb0) done; x1 stays in flight across barrier
    BAR();
    SCHED0();

    // ---------------- stage A: 8 k-steps, 1 counted barrier each ----------
    STEP_A(0, S0, S1, 4);
    STEP_A(1, S1, S0, 4);
    STEP_A(2, S0, S1, 4);
    STEP_A(3, S1, S0, 4);
    STEP_A(4, S0, S1, 4);
    STEP_A(5, S1, S0, 4);
    STEP_A(6, S0, S1, 0);  // no xload(8): drain glds fully
    STEP_A(7, S1, S0, 0);

    // ---------------- transition: W2 ring prime + H1t write ---------------
    W2STAGE(0, 0);
    SCHED0();
    W2STAGE(1, 1);
    #pragma unroll
    for (int mi = 0; mi < 4; ++mi)
        #pragma unroll
        for (int ni = 0; ni < 4; ++ni)
            #pragma unroll
            for (int r = 0; r < 4; ++r) {
                int row = mi * 16 + quad * 4 + r;
                int col = wn + ni * 16 + l15;
                int slot = (col >> 3) ^ (row & 7);
                lds[row * 256 + slot * 8 + (col & 7)] = f2bf(lrelu(acc[mi][ni][r]));
            }
    WAITV(4);              // kb0 landed; kb1 in flight across barrier
    BAR();
    SCHED0();

    #pragma unroll
    for (int mi = 0; mi < 4; ++mi)
        #pragma unroll
        for (int ni = 0; ni < 4; ++ni)
            acc[mi][ni] = (f32x4){0.f, 0.f, 0.f, 0.f};

    // ---------------- stage B: 8 k-steps, 3-deep W2 ring ------------------
    STEP_B(0, 4);
    STEP_B(1, 4);
    STEP_B(2, 4);
    STEP_B(3, 4);
    STEP_B(4, 4);
    STEP_B(5, 4);
    STEP_B(6, 0);
    STEP_B(7, 0);

    // ---------------- W3-dot epilogue -------------------------------------
    float* red = (float*)(lds + 16384);   // overlays W2 buf0 (dead)
    float w3v[4];
    #pragma unroll
    for (int ni = 0; ni < 4; ++ni)
        w3v[ni] = W3[(size_t)p * HW + wn + ni * 16 + l15];
    float part[4][4];
    #pragma unroll
    for (int mi = 0; mi < 4; ++mi) {
        #pragma unroll
        for (int r = 0; r < 4; ++r) {
            float s = 0.f;
            #pragma unroll
            for (int ni = 0; ni < 4; ++ni)
                s += lrelu(acc[mi][ni][r]) * w3v[ni];
            part[mi][r] = s;
        }
    }
    #pragma unroll
    for (int off = 1; off < 16; off <<= 1)
        #pragma unroll
        for (int mi = 0; mi < 4; ++mi)
            #pragma unroll
            for (int r = 0; r < 4; ++r)
                part[mi][r] += __shfl_xor(part[mi][r], off);
    if (l15 == 0)
        #pragma unroll
        for (int mi = 0; mi < 4; ++mi)
            #pragma unroll
            for (int r = 0; r < 4; ++r)
                red[wave * 64 + mi * 16 + quad * 4 + r] = part[mi][r];
    __syncthreads();
    if (t < 64) {
        float s = red[0 * 64 + t] + red[1 * 64 + t] + red[2 * 64 + t] + red[3 * 64 + t];
        pvec[(size_t)p * BATCH + bm0 + t] = lrelu(s);
    }
#undef XLOAD
#undef APACK
#undef B1STAGE
#undef MFMA_A
#undef W2STAGE
#undef MFMA_B
#undef STEP_A
#undef STEP_B
}

// ---------------------------------------------------------------------------
// Per-pathway batch stats: mean, invstd, var.  64 blocks, one per pathway.
// ---------------------------------------------------------------------------
__global__ __launch_bounds__(256)
void stats_k(const float* __restrict__ pvec, float* __restrict__ stat) {
    const int p = blockIdx.x;
    float s = 0.f, q = 0.f;
    for (int i = threadIdx.x; i < BATCH; i += 256) {
        float v = pvec[(size_t)p * BATCH + i];
        s += v; q += v * v;
    }
    #pragma unroll
    for (int off = 32; off; off >>= 1) {
        s += __shfl_down(s, off);
        q += __shfl_down(q, off);
    }
    __shared__ float ls[4], lq[4];
    const int wave = threadIdx.x >> 6, lane = threadIdx.x & 63;
    if (lane == 0) { ls[wave] = s; lq[wave] = q; }
    __syncthreads();
    if (threadIdx.x == 0) {
        float S = ls[0] + ls[1] + ls[2] + ls[3];
        float Q = lq[0] + lq[1] + lq[2] + lq[3];
        float mean = S * (1.f / BATCH);
        float var  = Q * (1.f / BATCH) - mean * mean;
        stat[p]       = mean;
        stat[64 + p]  = rsqrtf(var + 1e-5f);
        stat[128 + p] = var;
    }
}

// ---------------------------------------------------------------------------
// Final head (unchanged).
// ---------------------------------------------------------------------------
__global__ __launch_bounds__(256)
void final_k(const float* __restrict__ pvec, const float* __restrict__ stat,
             const float* __restrict__ gamma, const float* __restrict__ beta,
             const float* __restrict__ x, const float* __restrict__ fc_w,
             const float* __restrict__ fc_b, float* __restrict__ out) {
    const int b = blockIdx.x * 256 + threadIdx.x;
    float nsq = 0.f;
    #pragma unroll
    for (int p = 0; p < PW; ++p) {
        float g = gamma[p], bt = beta[p], var = stat[128 + p], inv = stat[64 + p];
        nsq += (float)BATCH * (g * g * var * inv * inv + bt * bt);
    }
    const float rn = rsqrtf(nsq);
    float acc = fc_b[0];
    #pragma unroll
    for (int p = 0; p < PW; ++p) {
        float pn = (pvec[(size_t)p * BATCH + b] - stat[p]) * stat[64 + p] * gamma[p] + beta[p];
        acc += pn * rn * fc_w[p];
    }
    #pragma unroll
    for (int c = 0; c < COV; ++c)
        acc += x[(size_t)b * XROW + PW * NV + c] * fc_w[PW + c];
    out[b] = 1.f / (1.f + __expf(-acc));
}

// ---------------------------------------------------------------------------
extern "C" void kernel_launch(void* const* d_in, const int* in_sizes, int n_in,
                              void* d_out, int out_size, void* d_ws, size_t ws_size,
                              hipStream_t stream) {
    const float* x     = (const float*)d_in[0];
    const float* W1    = (const float*)d_in[1];
    const float* W2    = (const float*)d_in[2];
    const float* W3    = (const float*)d_in[3];
    const float* gamma = (const float*)d_in[4];
    const float* beta  = (const float*)d_in[5];
    const float* fc_w  = (const float*)d_in[6];
    const float* fc_b  = (const float*)d_in[7];
    float* out = (float*)d_out;

    char* ws = (char*)d_ws;
    size_t off = 0;
    unsigned short* W1I = (unsigned short*)(ws + off); off += (size_t)PW * NV * HW * 2;  // 16.78 MB
    unsigned short* W2I = (unsigned short*)(ws + off); off += (size_t)PW * HW * HW * 2;  //  8.39 MB
    float* pvec = (float*)(ws + off); off += (size_t)PW * BATCH * 4;                      //  0.5 MB
    float* stat = (float*)(ws + off); off += 256 * 4;

    transpose_all<<<dim3(512 + 256), 256, 0, stream>>>(W1, W2, W1I, W2I);
    pathway_fused<<<dim3(2048), 256, 0, stream>>>(x, W1I, W2I, W3, pvec);
    stats_k<<<PW, 256, 0, stream>>>(pvec, stat);
    final_k<<<BATCH / 256, 256, 0, stream>>>(pvec, stat, gamma, beta, x, fc_w, fc_b, out);
}

// Round 6
// 455.752 us; speedup vs baseline: 1.1178x; 1.0556x over previous
//
#include <hip/hip_runtime.h>
#include <hip/hip_bf16.h>

#define PW 64
#define NV 512
#define HW 256
#define COV 16
#define BATCH 2048
#define XROW (PW * NV + COV)   // 32784
#define IMG 16384              // W1 image: 256 n x 64 k shorts (32 KB), slot = g ^ (n&7)
#define IMG2 8192              // W2 image: 256 n x 32 k shorts (16 KB), slot = g ^ ((n>>1)&3)

typedef short s16x8 __attribute__((ext_vector_type(8)));
typedef float f32x4 __attribute__((ext_vector_type(4)));

__device__ __forceinline__ unsigned short f2bf(float f) {
    union { float f; unsigned int u; } v;
    v.f = f;
    unsigned int u = v.u;
    unsigned int r = (u + 0x7fffu + ((u >> 16) & 1u)) >> 16;   // RNE
    return (unsigned short)r;
}

__device__ __forceinline__ unsigned int pack2(float a, float b) {
    __hip_bfloat162 h = __float22bfloat162_rn(float2{a, b});
    union { __hip_bfloat162 h; unsigned int u; } c;
    c.h = h;
    return c.u;
}

__device__ __forceinline__ float lrelu(float v) { return v >= 0.f ? v : 0.2f * v; }

__device__ __forceinline__ void gl_lds16(const void* g, void* l) {
    __builtin_amdgcn_global_load_lds(
        (const __attribute__((address_space(1))) void*)g,
        (__attribute__((address_space(3))) void*)l, 16, 0, 0);
}

#define WAITV(n) asm volatile("s_waitcnt vmcnt(" #n ") lgkmcnt(0)" ::: "memory")
#define BAR()    __builtin_amdgcn_s_barrier()
#define SCHED0() __builtin_amdgcn_sched_barrier(0)

// ---------------------------------------------------------------------------
// Weight prep (unchanged).
// W1 -> 8 images/pathway of 32 KB: shorts[n*64+s*8+j] = W1[kb*64+(s^(n&7))*8+j][n]
// W2 -> 8 images/pathway of 16 KB: shorts[n*32+s*8+j] = W2[kb*32+(s^((n>>1)&3))*8+j][n]
// ---------------------------------------------------------------------------
__global__ __launch_bounds__(256)
void transpose_all(const float* __restrict__ W1, const float* __restrict__ W2,
                   unsigned short* __restrict__ W1I, unsigned short* __restrict__ W2I) {
    __shared__ float tile[64][260];
    int bx = blockIdx.x;
    const int t = threadIdx.x;
    const bool isW1 = bx < 512;
    const float* src;
    if (isW1) {
        int p = bx >> 3, kb = bx & 7;
        src = W1 + ((size_t)p * NV + kb * 64) * HW;
    } else {
        int b2 = bx - 512;
        int p = b2 >> 2, kb64 = b2 & 3;
        src = W2 + ((size_t)p * HW + kb64 * 64) * HW;
    }
    #pragma unroll
    for (int i = 0; i < 16; ++i) {
        int idx = t + i * 256;
        int r = idx >> 6, c4 = (idx & 63) << 2;
        *(float4*)&tile[r][c4] = *(const float4*)(src + (size_t)r * HW + c4);
    }
    __syncthreads();
    if (isW1) {
        int p = bx >> 3, kb = bx & 7;
        unsigned short* dst = W1I + (size_t)(p * 8 + kb) * IMG;
        #pragma unroll
        for (int pass = 0; pass < 8; ++pass) {
            int idx = pass * 256 + t;
            int n = idx >> 3, s = idx & 7;
            int g = s ^ (n & 7);
            unsigned short v[8];
            #pragma unroll
            for (int j = 0; j < 8; ++j)
                v[j] = f2bf(tile[g * 8 + j][n]);
            *(s16x8*)(dst + (size_t)idx * 8) = *(s16x8*)v;
        }
    } else {
        int b2 = bx - 512;
        int p = b2 >> 2, kb64 = b2 & 3;
        unsigned short* dst = W2I + (size_t)(p * 8 + kb64 * 2) * IMG2;
        #pragma unroll
        for (int pass = 0; pass < 8; ++pass) {
            int idx = pass * 256 + t;
            int h = idx >> 10;
            int rem = idx & 1023;
            int n = rem >> 2, s = rem & 3;
            int g = s ^ ((n >> 1) & 3);
            int krow = h * 32 + g * 8;
            unsigned short v[8];
            #pragma unroll
            for (int j = 0; j < 8; ++j)
                v[j] = f2bf(tile[krow + j][n]);
            *(s16x8*)(dst + (size_t)h * IMG2 + n * 32 + s * 8) = *(s16x8*)v;
        }
    }
}

// ---------------------------------------------------------------------------
// FULLY-FUSED pathway kernel, BM=256 (4x fewer weight re-reads: 8 blocks per
// pathway instead of 32 -> ~200 MB instead of ~800 MB L3 weight traffic).
// 512 threads = 8 waves (2m x 4n), wave tile 128 rows x 64 cols.
// LDS arena 160 KB (1 block/CU):
//   stage A: As dbuf 2x32K [0:64K), Bs dbuf 2x32K [64K:128K)
//   stage B: H1t 128K [0:128K) (overlay), W2 dbuf 2x16K [128K:160K)
// Counted-vmcnt pipeline (T4): per A-step issue glds(t+1)[4] + xload(t+2)[8];
// WAITV(8) at barrier leaves x-loads in flight (2-step coverage).
// ---------------------------------------------------------------------------
__global__ __launch_bounds__(512, 2)
void pathway_fused(const float* __restrict__ x, const unsigned short* __restrict__ W1I,
                   const unsigned short* __restrict__ W2I, const float* __restrict__ W3,
                   float* __restrict__ pvec) {
    __shared__ __align__(16) unsigned short lds[81920];   // 160 KB arena

    const int lin = blockIdx.x;            // 0..511
    const int xcd = lin & 7;
    const int idx = lin >> 3;              // 0..63
    const int p   = xcd * 8 + (idx >> 3);  // each XCD owns 8 whole pathways
    const int mt  = idx & 7;
    const int bm0 = mt * 256;

    const int t = threadIdx.x;
    const int lane = t & 63;
    const int wave = t >> 6;       // 0..7
    const int wm   = wave >> 2;    // 0..1  (row half)
    const int wn   = wave & 3;     // 0..3  (64-col slice)
    const int l15  = lane & 15;
    const int quad = lane >> 4;

    const float* Ap          = x   + (size_t)p * NV;
    const unsigned short* B1 = W1I + (size_t)p * 8 * IMG;
    const unsigned short* B2 = W2I + (size_t)p * 8 * IMG2;

    // per-thread As staging addresses (8 uint2 writes, swizzled)
    int arow[8], acolc[8], aoff[8];
    #pragma unroll
    for (int i = 0; i < 8; ++i) {
        int ii = t + i * 512;          // 0..4095
        arow[i]  = ii >> 4;            // 0..255
        acolc[i] = (ii & 15) * 4;      // 0..60
        int slot = (acolc[i] >> 3) ^ (arow[i] & 7);
        aoff[i]  = arow[i] * 64 + slot * 8 + (acolc[i] & 7);
    }

    float4 S[8];
    f32x4 acc[8][4] = {};

#define XLOAD(k0) { \
    _Pragma("unroll") \
    for (int i = 0; i < 8; ++i) \
        S[i] = *(const float4*)(Ap + (size_t)(bm0 + arow[i]) * XROW + (k0) + acolc[i]); }

#define APACK(buf) { \
    unsigned short* Asb = lds + (buf) * 16384; \
    _Pragma("unroll") \
    for (int i = 0; i < 8; ++i) { \
        uint2 u; \
        u.x = pack2(S[i].x, S[i].y); \
        u.y = pack2(S[i].z, S[i].w); \
        *(uint2*)&Asb[aoff[i]] = u; } }

#define B1STAGE(buf, kb) { \
    const unsigned short* img = B1 + (size_t)(kb) * IMG; \
    _Pragma("unroll") \
    for (int c = 0; c < 4; ++c) { \
        int off = wave * 4096 + c * 1024; \
        gl_lds16((const char*)img + off + lane * 16, \
                 (char*)lds + 65536 + (buf) * 32768 + off); } }

#define MFMA_A(buf) { \
    const unsigned short* Asb = lds + (buf) * 16384; \
    const unsigned short* Bsb = lds + 32768 + (buf) * 16384; \
    __builtin_amdgcn_s_setprio(1); \
    _Pragma("unroll") \
    for (int kk = 0; kk < 64; kk += 32) { \
        s16x8 af[8], bfr[4]; \
        _Pragma("unroll") \
        for (int mi = 0; mi < 8; ++mi) { \
            int row = wm * 128 + mi * 16 + l15; \
            int slot = ((kk >> 3) + quad) ^ (row & 7); \
            af[mi] = *(const s16x8*)&Asb[row * 64 + slot * 8]; } \
        _Pragma("unroll") \
        for (int ni = 0; ni < 4; ++ni) { \
            int row = wn * 64 + ni * 16 + l15; \
            int slot = ((kk >> 3) + quad) ^ (row & 7); \
            bfr[ni] = *(const s16x8*)&Bsb[row * 64 + slot * 8]; } \
        _Pragma("unroll") \
        for (int mi = 0; mi < 8; ++mi) \
            _Pragma("unroll") \
            for (int ni = 0; ni < 4; ++ni) \
                acc[mi][ni] = __builtin_amdgcn_mfma_f32_16x16x32_bf16( \
                    af[mi], bfr[ni], acc[mi][ni], 0, 0, 0); } \
    __builtin_amdgcn_s_setprio(0); }

#define W2STAGE(buf, kb) { \
    const unsigned short* img = B2 + (size_t)(kb) * IMG2; \
    _Pragma("unroll") \
    for (int c = 0; c < 2; ++c) { \
        int off = wave * 2048 + c * 1024; \
        gl_lds16((const char*)img + off + lane * 16, \
                 (char*)lds + 131072 + (buf) * 16384 + off); } }

#define MFMA_B(buf, kb) { \
    const unsigned short* W2b = lds + 65536 + (buf) * 8192; \
    __builtin_amdgcn_s_setprio(1); \
    { \
        s16x8 af[8], bfr[4]; \
        _Pragma("unroll") \
        for (int mi = 0; mi < 8; ++mi) { \
            int row = wm * 128 + mi * 16 + l15; \
            int slot = ((kb) * 4 + quad) ^ (row & 7); \
            af[mi] = *(const s16x8*)&lds[row * 256 + slot * 8]; } \
        _Pragma("unroll") \
        for (int ni = 0; ni < 4; ++ni) { \
            int row = wn * 64 + ni * 16 + l15; \
            int slot = quad ^ ((row >> 1) & 3); \
            bfr[ni] = *(const s16x8*)&W2b[row * 32 + slot * 8]; } \
        _Pragma("unroll") \
        for (int mi = 0; mi < 8; ++mi) \
            _Pragma("unroll") \
            for (int ni = 0; ni < 4; ++ni) \
                acc[mi][ni] = __builtin_amdgcn_mfma_f32_16x16x32_bf16( \
                    af[mi], bfr[ni], acc[mi][ni], 0, 0, 0); \
    } \
    __builtin_amdgcn_s_setprio(0); }

// stage-A step: entry outstanding [x(t+1) 8]; issue glds(t+1)[4], pack(t+1)
// (compiler vmcnt(4) waits x only), xload(t+2)[8]; WAITV(8) keeps x in flight
#define STEP_A(tt, WN) { \
    if ((tt) + 1 < 8) B1STAGE(1 - ((tt) & 1), (tt) + 1); \
    SCHED0(); \
    if ((tt) + 1 < 8) APACK(1 - ((tt) & 1)); \
    if ((tt) + 2 < 8) XLOAD(((tt) + 2) * 64); \
    SCHED0(); \
    MFMA_A((tt) & 1); \
    WAITV(WN); \
    BAR(); \
    SCHED0(); }

#define STEP_B(tt) { \
    if ((tt) + 1 < 8) W2STAGE(1 - ((tt) & 1), (tt) + 1); \
    SCHED0(); \
    MFMA_B((tt) & 1, (tt)); \
    WAITV(0); \
    BAR(); \
    SCHED0(); }

    // ---------------- stage A prologue ------------------------------------
    XLOAD(0);
    SCHED0();
    B1STAGE(0, 0);
    SCHED0();
    APACK(0);              // compiler waits x0 (vmcnt(4)); glds0 in flight
    XLOAD(64);
    WAITV(8);              // glds0 done; x1 in flight across barrier
    BAR();
    SCHED0();

    // ---------------- stage A: 8 k-steps ----------------------------------
    STEP_A(0, 8);
    STEP_A(1, 8);
    STEP_A(2, 8);
    STEP_A(3, 8);
    STEP_A(4, 8);
    STEP_A(5, 8);
    STEP_A(6, 0);          // no xload(8): drain
    STEP_A(7, 0);

    // ---------------- transition: W2 prime + H1t write (overlay) ----------
    W2STAGE(0, 0);         // latency overlaps the H1t writes below
    SCHED0();
    #pragma unroll
    for (int mi = 0; mi < 8; ++mi)
        #pragma unroll
        for (int ni = 0; ni < 4; ++ni)
            #pragma unroll
            for (int r = 0; r < 4; ++r) {
                int row = wm * 128 + mi * 16 + quad * 4 + r;
                int col = wn * 64 + ni * 16 + l15;
                int slot = (col >> 3) ^ (row & 7);
                lds[row * 256 + slot * 8 + (col & 7)] = f2bf(lrelu(acc[mi][ni][r]));
            }
    WAITV(0);
    BAR();
    SCHED0();

    #pragma unroll
    for (int mi = 0; mi < 8; ++mi)
        #pragma unroll
        for (int ni = 0; ni < 4; ++ni)
            acc[mi][ni] = (f32x4){0.f, 0.f, 0.f, 0.f};

    // ---------------- stage B: 8 k-steps (BK=32) --------------------------
    STEP_B(0);
    STEP_B(1);
    STEP_B(2);
    STEP_B(3);
    STEP_B(4);
    STEP_B(5);
    STEP_B(6);
    STEP_B(7);

    // ---------------- W3-dot epilogue -------------------------------------
    float* red = (float*)lds;        // overlays dead H1t (4 KB)
    float w3v[4];
    #pragma unroll
    for (int ni = 0; ni < 4; ++ni)
        w3v[ni] = W3[(size_t)p * HW + wn * 64 + ni * 16 + l15];
    float part[8][4];
    #pragma unroll
    for (int mi = 0; mi < 8; ++mi) {
        #pragma unroll
        for (int r = 0; r < 4; ++r) {
            float s = 0.f;
            #pragma unroll
            for (int ni = 0; ni < 4; ++ni)
                s += lrelu(acc[mi][ni][r]) * w3v[ni];
            part[mi][r] = s;
        }
    }
    #pragma unroll
    for (int off = 1; off < 16; off <<= 1)
        #pragma unroll
        for (int mi = 0; mi < 8; ++mi)
            #pragma unroll
            for (int r = 0; r < 4; ++r)
                part[mi][r] += __shfl_xor(part[mi][r], off);
    if (l15 == 0)
        #pragma unroll
        for (int mi = 0; mi < 8; ++mi)
            #pragma unroll
            for (int r = 0; r < 4; ++r)
                red[wn * 256 + wm * 128 + mi * 16 + quad * 4 + r] = part[mi][r];
    __syncthreads();
    if (t < 256) {
        float s = red[0 * 256 + t] + red[1 * 256 + t] + red[2 * 256 + t] + red[3 * 256 + t];
        pvec[(size_t)p * BATCH + bm0 + t] = lrelu(s);
    }
#undef XLOAD
#undef APACK
#undef B1STAGE
#undef MFMA_A
#undef W2STAGE
#undef MFMA_B
#undef STEP_A
#undef STEP_B
}

// ---------------------------------------------------------------------------
// Per-pathway batch stats (unchanged).
// ---------------------------------------------------------------------------
__global__ __launch_bounds__(256)
void stats_k(const float* __restrict__ pvec, float* __restrict__ stat) {
    const int p = blockIdx.x;
    float s = 0.f, q = 0.f;
    for (int i = threadIdx.x; i < BATCH; i += 256) {
        float v = pvec[(size_t)p * BATCH + i];
        s += v; q += v * v;
    }
    #pragma unroll
    for (int off = 32; off; off >>= 1) {
        s += __shfl_down(s, off);
        q += __shfl_down(q, off);
    }
    __shared__ float ls[4], lq[4];
    const int wave = threadIdx.x >> 6, lane = threadIdx.x & 63;
    if (lane == 0) { ls[wave] = s; lq[wave] = q; }
    __syncthreads();
    if (threadIdx.x == 0) {
        float S = ls[0] + ls[1] + ls[2] + ls[3];
        float Q = lq[0] + lq[1] + lq[2] + lq[3];
        float mean = S * (1.f / BATCH);
        float var  = Q * (1.f / BATCH) - mean * mean;
        stat[p]       = mean;
        stat[64 + p]  = rsqrtf(var + 1e-5f);
        stat[128 + p] = var;
    }
}

// ---------------------------------------------------------------------------
// Final head (unchanged).
// ---------------------------------------------------------------------------
__global__ __launch_bounds__(256)
void final_k(const float* __restrict__ pvec, const float* __restrict__ stat,
             const float* __restrict__ gamma, const float* __restrict__ beta,
             const float* __restrict__ x, const float* __restrict__ fc_w,
             const float* __restrict__ fc_b, float* __restrict__ out) {
    const int b = blockIdx.x * 256 + threadIdx.x;
    float nsq = 0.f;
    #pragma unroll
    for (int p = 0; p < PW; ++p) {
        float g = gamma[p], bt = beta[p], var = stat[128 + p], inv = stat[64 + p];
        nsq += (float)BATCH * (g * g * var * inv * inv + bt * bt);
    }
    const float rn = rsqrtf(nsq);
    float acc = fc_b[0];
    #pragma unroll
    for (int p = 0; p < PW; ++p) {
        float pn = (pvec[(size_t)p * BATCH + b] - stat[p]) * stat[64 + p] * gamma[p] + beta[p];
        acc += pn * rn * fc_w[p];
    }
    #pragma unroll
    for (int c = 0; c < COV; ++c)
        acc += x[(size_t)b * XROW + PW * NV + c] * fc_w[PW + c];
    out[b] = 1.f / (1.f + __expf(-acc));
}

// ---------------------------------------------------------------------------
extern "C" void kernel_launch(void* const* d_in, const int* in_sizes, int n_in,
                              void* d_out, int out_size, void* d_ws, size_t ws_size,
                              hipStream_t stream) {
    const float* x     = (const float*)d_in[0];
    const float* W1    = (const float*)d_in[1];
    const float* W2    = (const float*)d_in[2];
    const float* W3    = (const float*)d_in[3];
    const float* gamma = (const float*)d_in[4];
    const float* beta  = (const float*)d_in[5];
    const float* fc_w  = (const float*)d_in[6];
    const float* fc_b  = (const float*)d_in[7];
    float* out = (float*)d_out;

    char* ws = (char*)d_ws;
    size_t off = 0;
    unsigned short* W1I = (unsigned short*)(ws + off); off += (size_t)PW * NV * HW * 2;  // 16.78 MB
    unsigned short* W2I = (unsigned short*)(ws + off); off += (size_t)PW * HW * HW * 2;  //  8.39 MB
    float* pvec = (float*)(ws + off); off += (size_t)PW * BATCH * 4;                      //  0.5 MB
    float* stat = (float*)(ws + off); off += 256 * 4;

    transpose_all<<<dim3(512 + 256), 256, 0, stream>>>(W1, W2, W1I, W2I);
    pathway_fused<<<dim3(512), 512, 0, stream>>>(x, W1I, W2I, W3, pvec);
    stats_k<<<PW, 256, 0, stream>>>(pvec, stat);
    final_k<<<BATCH / 256, 256, 0, stream>>>(pvec, stat, gamma, beta, x, fc_w, fc_b, out);
}